// Round 7
// baseline (355.789 us; speedup 1.0000x reference)
//
#include <hip/hip_runtime.h>

// NodeEncoder: RoIAlign -> FC1(12544->512)+BN+ReLU -> FC2(512->512)+BN+ReLU -> max over K=8
// F=64 C=256 H=W=40, N=512 K=8 (R=4096), ROI=7, HID=D=512

typedef __bf16 bf16x8 __attribute__((ext_vector_type(8)));
typedef float f32x4 __attribute__((ext_vector_type(4)));
typedef ushort us8v __attribute__((ext_vector_type(8)));

#define BN_EPS 1e-3f

__device__ __forceinline__ ushort f2bf(float f) {
  union { float f; unsigned u; } v; v.f = f;
  unsigned r = (v.u + 0x7FFFu + ((v.u >> 16) & 1u)) >> 16;
  return (ushort)r;
}
__device__ __forceinline__ float bf2f(ushort b) {
  union { unsigned u; float f; } v; v.u = ((unsigned)b) << 16;
  return v.f;
}
__device__ __forceinline__ void async16(const void* g, void* l) {
  __builtin_amdgcn_global_load_lds((const __attribute__((address_space(1))) void*)g,
                                   (__attribute__((address_space(3))) void*)l, 16, 0, 0);
}

// ------- 1. images [64,256,40,40] f32 -> imgTb [64,40,40,256] bf16 -----------------------
__global__ __launch_bounds__(256) void transpose_kernel(const float* __restrict__ img,
                                                        ushort* __restrict__ imgTb) {
  __shared__ ushort lds[64 * 260];  // [pixel][channel], pitch 260
  const int f = blockIdx.x, p0 = blockIdx.y * 64;
  const int tid = threadIdx.x;
  const float* src = img + (size_t)f * 409600 + p0;
#pragma unroll
  for (int m = 0; m < 4; ++m) {
    int g = m * 256 + tid;
    int cg = g >> 4;   // channel group (4 ch), 0..63
    int pg = g & 15;   // pixel group (4 px)
    float4 v[4];
#pragma unroll
    for (int j = 0; j < 4; ++j)
      v[j] = *(const float4*)(src + (size_t)(cg * 4 + j) * 1600 + pg * 4);
#pragma unroll
    for (int i = 0; i < 4; ++i) {
      ushort4 o;
      o.x = f2bf((&v[0].x)[i]);
      o.y = f2bf((&v[1].x)[i]);
      o.z = f2bf((&v[2].x)[i]);
      o.w = f2bf((&v[3].x)[i]);
      *(ushort4*)(&lds[(pg * 4 + i) * 260 + cg * 4]) = o;
    }
  }
  __syncthreads();
  ushort* dst = imgTb + ((size_t)f * 1600 + p0) * 256;
#pragma unroll
  for (int q = 0; q < 8; ++q) {
    int p = q * 8 + (tid >> 5);  // pixel 0..63
    int cg8 = tid & 31;          // 8-channel group
    ushort4 a = *(const ushort4*)(&lds[p * 260 + cg8 * 8]);
    ushort4 b = *(const ushort4*)(&lds[p * 260 + cg8 * 8 + 4]);
    us8v o;
    o[0] = a.x; o[1] = a.y; o[2] = a.z; o[3] = a.w;
    o[4] = b.x; o[5] = b.y; o[6] = b.z; o[7] = b.w;
    *(us8v*)(dst + (size_t)p * 256 + cg8 * 8) = o;  // 512 B/pixel, fully coalesced
  }
}

// ------- 2. w1 [512][256][49] f32 -> w1b [512][49*256] bf16 (k = p*256+c), LDS staged ----
__global__ __launch_bounds__(256) void w1_convert(const float* __restrict__ w1,
                                                  ushort* __restrict__ w1b) {
  __shared__ float t[49 * 257];  // [p][c], pitch 257 floats
  const int o = blockIdx.x;
  const float* src = w1 + (size_t)o * 12544;
  for (int j = threadIdx.x; j < 12544; j += 256) {  // coalesced read, j = c*49+p
    int c = j / 49, p = j - c * 49;
    t[p * 257 + c] = src[j];
  }
  __syncthreads();
  ushort* dst = w1b + (size_t)o * 12544;
  for (int k = threadIdx.x; k < 12544; k += 256) {  // coalesced write, k = p*256+c
    int p = k >> 8, c = k & 255;
    dst[k] = f2bf(t[p * 257 + c]);
  }
}

__global__ __launch_bounds__(256) void w2_convert(const float* __restrict__ w2,
                                                  ushort* __restrict__ w2b) {
  size_t i = (size_t)blockIdx.x * 256 + threadIdx.x;  // exactly 512*512
  w2b[i] = f2bf(w2[i]);
}

// ------- 3. RoIAlign (bf16 image) -> A [4096][12544] bf16, k = (py*7+px)*256 + c ---------
__global__ __launch_bounds__(256) void roi_kernel(const ushort* __restrict__ imgTb,
                                                  const int* __restrict__ kf,
                                                  const float* __restrict__ boxes,
                                                  ushort* __restrict__ A) {
  __shared__ int sy0[49], sx0[49], sy1[49], sx1[49];
  __shared__ float sw00[49], sw01[49], sw10[49], sw11[49];
  __shared__ int sf;
  const int r = blockIdx.x, tid = threadIdx.x;
  if (tid == 0) sf = kf[r];
  if (tid < 49) {
    int py = tid / 7, px = tid % 7;
    float x1 = boxes[r * 4 + 0] * 40.f, y1 = boxes[r * 4 + 1] * 40.f;
    float x2 = boxes[r * 4 + 2] * 40.f, y2 = boxes[r * 4 + 3] * 40.f;
    float bw = (x2 - x1) * (1.f / 7.f), bh = (y2 - y1) * (1.f / 7.f);
    float X = x1 + (px + 0.5f) * bw, Y = y1 + (py + 0.5f) * bh;
    bool valid = (X > -1.f) && (X < 40.f) && (Y > -1.f) && (Y < 40.f);
    float x = fminf(fmaxf(X, 0.f), 39.f), y = fminf(fmaxf(Y, 0.f), 39.f);
    float x0f = floorf(x), y0f = floorf(y);
    int x0 = (int)x0f, y0 = (int)y0f;
    int x1i = min(x0 + 1, 39), y1i = min(y0 + 1, 39);
    float lx = x - x0f, ly = y - y0f;
    float vm = valid ? 1.f : 0.f;
    sx0[tid] = x0; sy0[tid] = y0; sx1[tid] = x1i; sy1[tid] = y1i;
    sw00[tid] = (1.f - ly) * (1.f - lx) * vm;
    sw01[tid] = (1.f - ly) * lx * vm;
    sw10[tid] = ly * (1.f - lx) * vm;
    sw11[tid] = ly * lx * vm;
  }
  __syncthreads();
  const int c8 = (tid & 31) * 8;  // 8 channels per thread (16B loads)
  const int pq = tid >> 5;        // position phase 0..7
  const ushort* base = imgTb + (size_t)sf * 409600 + c8;
  ushort* outp = A + (size_t)r * 12544 + c8;
  for (int p = pq; p < 49; p += 8) {
    const us8v a = *(const us8v*)(base + (size_t)(sy0[p] * 40 + sx0[p]) * 256);
    const us8v b = *(const us8v*)(base + (size_t)(sy0[p] * 40 + sx1[p]) * 256);
    const us8v c = *(const us8v*)(base + (size_t)(sy1[p] * 40 + sx0[p]) * 256);
    const us8v d = *(const us8v*)(base + (size_t)(sy1[p] * 40 + sx1[p]) * 256);
    float w00 = sw00[p], w01 = sw01[p], w10 = sw10[p], w11 = sw11[p];
    us8v o;
#pragma unroll
    for (int k = 0; k < 8; ++k)
      o[k] = f2bf(bf2f(a[k]) * w00 + bf2f(b[k]) * w01 + bf2f(c[k]) * w10 + bf2f(d[k]) * w11);
    *(us8v*)(outp + (size_t)p * 256) = o;
  }
}

// ------- 4. GEMM1: [4096,12544]x[512,12544]^T bf16, BK=64, split-K=7, bf16 partials ------
// Split into two half-row dispatches (rowOff) so the profiler top-5 exposes kernels >40us.
// LDS swizzle (BK=64, 8 chunks/row): slot s of row R holds global chunk s ^ (R&7).
__global__ __launch_bounds__(256) void gemm1_kernel(const ushort* __restrict__ A,
                                                    const ushort* __restrict__ B,
                                                    ushort* __restrict__ P,
                                                    int rowOff) {
  constexpr int K = 12544;
  constexpr int KS = 1792;  // = K/7, 28 iters of 64
  __shared__ __align__(16) ushort sA[128 * 64];  // 16 KB
  __shared__ __align__(16) ushort sB[128 * 64];  // 16 KB
  const int tid = threadIdx.x;
  const int lane = tid & 63, wave = tid >> 6;
  const int wm = wave >> 1, wn = wave & 1;
  const int r16 = lane & 15, quad = lane >> 4;
  const int r0 = (blockIdx.x + rowOff) * 128, c0 = blockIdx.y * 128;
  const int kStart = blockIdx.z * KS, kEnd = kStart + KS;
  const ushort* Ab = A + (size_t)r0 * K;
  const ushort* Bb = B + (size_t)c0 * K;
  const int row8 = tid >> 3;                        // 0..31
  const int koff = (((tid & 7) ^ (row8 & 7))) * 8;  // swizzled source chunk offset
  const int sw = r16 & 7;
  f32x4 acc[4][4] = {};
  for (int kk = kStart; kk < kEnd; kk += 64) {
    __syncthreads();
#pragma unroll
    for (int s = 0; s < 4; ++s)
      async16(Ab + (size_t)(s * 32 + row8) * K + kk + koff, (char*)sA + s * 4096 + tid * 16);
#pragma unroll
    for (int s = 0; s < 4; ++s)
      async16(Bb + (size_t)(s * 32 + row8) * K + kk + koff, (char*)sB + s * 4096 + tid * 16);
    __syncthreads();
#pragma unroll
    for (int h = 0; h < 2; ++h) {
      const int slot = ((h * 4 + quad) ^ sw) * 8;
      bf16x8 af[4], bfr[4];
#pragma unroll
      for (int i = 0; i < 4; ++i)
        af[i] = *(const bf16x8*)(sA + (wm * 64 + i * 16 + r16) * 64 + slot);
#pragma unroll
      for (int j = 0; j < 4; ++j)
        bfr[j] = *(const bf16x8*)(sB + (wn * 64 + j * 16 + r16) * 64 + slot);
#pragma unroll
      for (int i = 0; i < 4; ++i)
#pragma unroll
        for (int j = 0; j < 4; ++j)
          acc[i][j] = __builtin_amdgcn_mfma_f32_16x16x32_bf16(af[i], bfr[j], acc[i][j], 0, 0, 0);
    }
  }
  ushort* Pz = P + ((size_t)blockIdx.z * 4096 + r0) * 512 + c0;
#pragma unroll
  for (int i = 0; i < 4; ++i)
#pragma unroll
    for (int j = 0; j < 4; ++j)
#pragma unroll
      for (int g = 0; g < 4; ++g)
        Pz[(size_t)(wm * 64 + i * 16 + quad * 4 + g) * 512 + (wn * 64 + j * 16 + r16)] =
            f2bf(acc[i][j][g]);
}

// ------- 5. combine 7 split-K bf16 partials + b1 + BN1 + ReLU -> h1 bf16 -----------------
__global__ __launch_bounds__(256) void combine_kernel(const ushort* __restrict__ P,
                                                      const float* __restrict__ b1,
                                                      const float* __restrict__ g1,
                                                      const float* __restrict__ bt1,
                                                      const float* __restrict__ m1,
                                                      const float* __restrict__ v1,
                                                      ushort* __restrict__ h1) {
  size_t i = (size_t)blockIdx.x * 256 + threadIdx.x;  // exactly 4096*512
  int col = (int)(i & 511);
  float x = 0.f;
#pragma unroll
  for (int z = 0; z < 7; ++z) x += bf2f(P[i + (size_t)z * 2097152]);
  float s = g1[col] * rsqrtf(v1[col] + BN_EPS);
  float val = fmaxf((x + b1[col] - m1[col]) * s + bt1[col], 0.f);
  h1[i] = f2bf(val);
}

// ------- 6. GEMM2 (64x128 tile, BK=64) + b2 + BN2 + ReLU + group-of-8 max -> out ---------
__global__ __launch_bounds__(256) void gemm2_kernel(const ushort* __restrict__ A,
                                                    const ushort* __restrict__ B,
                                                    const float* __restrict__ b2,
                                                    const float* __restrict__ g2,
                                                    const float* __restrict__ bt2,
                                                    const float* __restrict__ m2,
                                                    const float* __restrict__ v2,
                                                    float* __restrict__ out) {
  constexpr int K = 512;
  __shared__ __align__(16) ushort sA[64 * 64];   // 8 KB
  __shared__ __align__(16) ushort sB[128 * 64];  // 16 KB
  __shared__ ushort st[64 * 128];                // post-activation tile for group-max
  const int tid = threadIdx.x;
  const int lane = tid & 63, wave = tid >> 6;
  const int wm = wave >> 1, wn = wave & 1;  // waves: 2 (rows) x 2 (cols)
  const int r16 = lane & 15, quad = lane >> 4;
  const int r0 = blockIdx.x * 64, c0 = blockIdx.y * 128;
  const ushort* Ab = A + (size_t)r0 * K;
  const ushort* Bb = B + (size_t)c0 * K;
  const int row8 = tid >> 3;
  const int koff = (((tid & 7) ^ (row8 & 7))) * 8;
  const int sw = r16 & 7;
  f32x4 acc[2][4] = {};
  for (int kk = 0; kk < K; kk += 64) {
    __syncthreads();
#pragma unroll
    for (int s = 0; s < 2; ++s)
      async16(Ab + (size_t)(s * 32 + row8) * K + kk + koff, (char*)sA + s * 4096 + tid * 16);
#pragma unroll
    for (int s = 0; s < 4; ++s)
      async16(Bb + (size_t)(s * 32 + row8) * K + kk + koff, (char*)sB + s * 4096 + tid * 16);
    __syncthreads();
#pragma unroll
    for (int h = 0; h < 2; ++h) {
      const int slot = ((h * 4 + quad) ^ sw) * 8;
      bf16x8 af[2], bfr[4];
#pragma unroll
      for (int i = 0; i < 2; ++i)
        af[i] = *(const bf16x8*)(sA + (wm * 32 + i * 16 + r16) * 64 + slot);
#pragma unroll
      for (int j = 0; j < 4; ++j)
        bfr[j] = *(const bf16x8*)(sB + (wn * 64 + j * 16 + r16) * 64 + slot);
#pragma unroll
      for (int i = 0; i < 2; ++i)
#pragma unroll
        for (int j = 0; j < 4; ++j)
          acc[i][j] = __builtin_amdgcn_mfma_f32_16x16x32_bf16(af[i], bfr[j], acc[i][j], 0, 0, 0);
    }
  }
  // epilogue: bias + BN + relu, stage to LDS
  float ss[4], tt[4], bbv[4];
#pragma unroll
  for (int j = 0; j < 4; ++j) {
    int c = c0 + wn * 64 + j * 16 + r16;
    float s = g2[c] * rsqrtf(v2[c] + BN_EPS);
    ss[j] = s; tt[j] = bt2[c] - m2[c] * s; bbv[j] = b2[c];
  }
#pragma unroll
  for (int i = 0; i < 2; ++i)
#pragma unroll
    for (int j = 0; j < 4; ++j)
#pragma unroll
      for (int g = 0; g < 4; ++g) {
        int rr = wm * 32 + i * 16 + quad * 4 + g;
        int cc = wn * 64 + j * 16 + r16;
        float x = (acc[i][j][g] + bbv[j]) * ss[j] + tt[j];
        st[rr * 128 + cc] = f2bf(fmaxf(x, 0.f));
      }
  __syncthreads();
  // 64 rows = 8 complete groups of 8; reduce and store (no atomics)
  for (int e = tid; e < 1024; e += 256) {
    int gg = e >> 7, cc = e & 127;
    float m = 0.f;  // relu output >= 0
#pragma unroll
    for (int k = 0; k < 8; ++k) m = fmaxf(m, bf2f(st[(gg * 8 + k) * 128 + cc]));
    out[(size_t)(r0 / 8 + gg) * 512 + c0 + cc] = m;
  }
}

extern "C" void kernel_launch(void* const* d_in, const int* in_sizes, int n_in,
                              void* d_out, int out_size, void* d_ws, size_t ws_size,
                              hipStream_t stream) {
  (void)in_sizes; (void)n_in; (void)out_size; (void)ws_size;
  const float* images = (const float*)d_in[0];
  const int* kf      = (const int*)d_in[1];
  const float* boxes = (const float*)d_in[2];
  const float* w1    = (const float*)d_in[3];
  const float* b1    = (const float*)d_in[4];
  const float* g1    = (const float*)d_in[5];
  const float* bt1   = (const float*)d_in[6];
  const float* m1    = (const float*)d_in[7];
  const float* v1    = (const float*)d_in[8];
  const float* w2    = (const float*)d_in[9];
  const float* b2    = (const float*)d_in[10];
  const float* g2    = (const float*)d_in[11];
  const float* bt2   = (const float*)d_in[12];
  const float* m2    = (const float*)d_in[13];
  const float* v2    = (const float*)d_in[14];
  float* out = (float*)d_out;

  char* ws = (char*)d_ws;
  // layout (bytes):  [ws_size >= 221 MB proven in round 1]
  //   A     @ 0          : 4096*12544*2 = 102,760,448
  //   w1b   @ 102,760,448: 512*12544*2  =  12,845,056
  //   w2b   @ 115,605,504: 512*512*2    =     524,288
  //   imgTb @ 116,129,792: 64*1600*256*2 = 52,428,800   (dead after roi_kernel)
  //   P     @ 116,129,792: 7*4096*512*2 = 29,360,128    (bf16 partials, aliases imgTb)
  //   h1    @ 149,684,224: 4096*512*2   =  4,194,304
  ushort* Abuf  = (ushort*)(ws + 0);
  ushort* w1b   = (ushort*)(ws + 102760448);
  ushort* w2b   = (ushort*)(ws + 115605504);
  ushort* imgTb = (ushort*)(ws + 116129792);
  ushort* P     = (ushort*)(ws + 116129792);
  ushort* h1    = (ushort*)(ws + 149684224);

  hipLaunchKernelGGL(transpose_kernel, dim3(64, 25), dim3(256), 0, stream, images, imgTb);
  hipLaunchKernelGGL(w1_convert, dim3(512), dim3(256), 0, stream, w1, w1b);
  hipLaunchKernelGGL(w2_convert, dim3(1024), dim3(256), 0, stream, w2, w2b);
  hipLaunchKernelGGL(roi_kernel, dim3(4096), dim3(256), 0, stream, imgTb, kf, boxes, Abuf);
  hipLaunchKernelGGL(gemm1_kernel, dim3(16, 4, 7), dim3(256), 0, stream, Abuf, w1b, P, 0);
  hipLaunchKernelGGL(gemm1_kernel, dim3(16, 4, 7), dim3(256), 0, stream, Abuf, w1b, P, 16);
  hipLaunchKernelGGL(combine_kernel, dim3(8192), dim3(256), 0, stream, P, b1, g1, bt1, m1, v1, h1);
  hipLaunchKernelGGL(gemm2_kernel, dim3(64, 4), dim3(256), 0, stream, h1, w2b, b2, g2, bt2, m2, v2, out);
}

// Round 9
// 337.821 us; speedup vs baseline: 1.0532x; 1.0532x over previous
//
#include <hip/hip_runtime.h>

// NodeEncoder: RoIAlign -> FC1(12544->512)+BN+ReLU -> FC2(512->512)+BN+ReLU -> max over K=8
// F=64 C=256 H=W=40, N=512 K=8 (R=4096), ROI=7, HID=D=512
// NOTE: harness re-poisons the 400MiB d_ws (~61us fill) + restores inputs (~45us) inside the
// timed region -> ~110us fixed overhead. Kernel budget is what we optimize.

typedef __bf16 bf16x8 __attribute__((ext_vector_type(8)));
typedef float f32x4 __attribute__((ext_vector_type(4)));
typedef ushort us8v __attribute__((ext_vector_type(8)));

#define BN_EPS 1e-3f

__device__ __forceinline__ ushort f2bf(float f) {
  union { float f; unsigned u; } v; v.f = f;
  unsigned r = (v.u + 0x7FFFu + ((v.u >> 16) & 1u)) >> 16;
  return (ushort)r;
}
__device__ __forceinline__ float bf2f(ushort b) {
  union { unsigned u; float f; } v; v.u = ((unsigned)b) << 16;
  return v.f;
}
__device__ __forceinline__ void async16(const void* g, void* l) {
  __builtin_amdgcn_global_load_lds((const __attribute__((address_space(1))) void*)g,
                                   (__attribute__((address_space(3))) void*)l, 16, 0, 0);
}

// ------- 1. images [64,256,40,40] f32 -> imgTb [64,40,40,256] bf16 -----------------------
__global__ __launch_bounds__(256) void transpose_kernel(const float* __restrict__ img,
                                                        ushort* __restrict__ imgTb) {
  __shared__ ushort lds[64 * 260];  // [pixel][channel], pitch 260
  const int f = blockIdx.x, p0 = blockIdx.y * 64;
  const int tid = threadIdx.x;
  const float* src = img + (size_t)f * 409600 + p0;
#pragma unroll
  for (int m = 0; m < 4; ++m) {
    int g = m * 256 + tid;
    int cg = g >> 4;   // channel group (4 ch), 0..63
    int pg = g & 15;   // pixel group (4 px)
    float4 v[4];
#pragma unroll
    for (int j = 0; j < 4; ++j)
      v[j] = *(const float4*)(src + (size_t)(cg * 4 + j) * 1600 + pg * 4);
#pragma unroll
    for (int i = 0; i < 4; ++i) {
      ushort4 o;
      o.x = f2bf((&v[0].x)[i]);
      o.y = f2bf((&v[1].x)[i]);
      o.z = f2bf((&v[2].x)[i]);
      o.w = f2bf((&v[3].x)[i]);
      *(ushort4*)(&lds[(pg * 4 + i) * 260 + cg * 4]) = o;
    }
  }
  __syncthreads();
  ushort* dst = imgTb + ((size_t)f * 1600 + p0) * 256;
#pragma unroll
  for (int q = 0; q < 8; ++q) {
    int p = q * 8 + (tid >> 5);  // pixel 0..63
    int cg8 = tid & 31;          // 8-channel group
    ushort4 a = *(const ushort4*)(&lds[p * 260 + cg8 * 8]);
    ushort4 b = *(const ushort4*)(&lds[p * 260 + cg8 * 8 + 4]);
    us8v o;
    o[0] = a.x; o[1] = a.y; o[2] = a.z; o[3] = a.w;
    o[4] = b.x; o[5] = b.y; o[6] = b.z; o[7] = b.w;
    *(us8v*)(dst + (size_t)p * 256 + cg8 * 8) = o;  // 512 B/pixel, fully coalesced
  }
}

// ------- 2. merged weight convert: w1 reorder->bf16, w2 ->bf16 ---------------------------
__global__ __launch_bounds__(256) void wconvert_kernel(const float* __restrict__ w1,
                                                       ushort* __restrict__ w1b,
                                                       const float* __restrict__ w2,
                                                       ushort* __restrict__ w2b) {
  const int b = blockIdx.x;
  if (b < 512) {
    __shared__ float t[49 * 257];  // [p][c], pitch 257 floats
    const float* src = w1 + (size_t)b * 12544;
    for (int j = threadIdx.x; j < 12544; j += 256) {  // coalesced read, j = c*49+p
      int c = j / 49, p = j - c * 49;
      t[p * 257 + c] = src[j];
    }
    __syncthreads();
    ushort* dst = w1b + (size_t)b * 12544;
    for (int k = threadIdx.x; k < 12544; k += 256) {  // coalesced write, k = p*256+c
      int p = k >> 8, c = k & 255;
      dst[k] = f2bf(t[p * 257 + c]);
    }
  } else {
    size_t i = (size_t)(b - 512) * 256 + threadIdx.x;  // exactly 512*512
    w2b[i] = f2bf(w2[i]);
  }
}

// ------- 3a. counting sort of RoIs by frame -> perm[4096] (single block, no global state)
__global__ __launch_bounds__(256) void sort_kernel(const int* __restrict__ kf,
                                                   int* __restrict__ perm) {
  __shared__ int cnt[64];
  __shared__ int base[64];
  const int tid = threadIdx.x;
  if (tid < 64) cnt[tid] = 0;
  __syncthreads();
  for (int r = tid; r < 4096; r += 256) atomicAdd(&cnt[kf[r]], 1);
  __syncthreads();
  if (tid == 0) {
    int acc = 0;
    for (int f = 0; f < 64; ++f) { base[f] = acc; acc += cnt[f]; }
  }
  __syncthreads();
  for (int r = tid; r < 4096; r += 256) {
    int p = atomicAdd(&base[kf[r]], 1);
    perm[p] = r;
  }
}

// ------- 3b. RoIAlign (bf16 image) -> A [4096][12544] bf16, k = (py*7+px)*256 + c --------
// XCD-locality: blocks with the same (blockIdx&7) land on the same XCD (round-robin
// heuristic); perm is frame-sorted, so each XCD walks ~8 consecutive frames -> corner
// gathers stay in that XCD's 4MB L2 instead of thrashing across all 64 frames (52MB).
__global__ __launch_bounds__(256) void roi_kernel(const ushort* __restrict__ imgTb,
                                                  const int* __restrict__ kf,
                                                  const float* __restrict__ boxes,
                                                  const int* __restrict__ perm,
                                                  ushort* __restrict__ A) {
  __shared__ int sy0[49], sx0[49], sy1[49], sx1[49];
  __shared__ float sw00[49], sw01[49], sw10[49], sw11[49];
  __shared__ int sf, sr;
  const int tid = threadIdx.x;
  if (tid == 0) {
    int r = perm[((blockIdx.x & 7) << 9) | (blockIdx.x >> 3)];
    sr = r;
    sf = kf[r];
  }
  __syncthreads();
  const int r = sr;
  if (tid < 49) {
    int py = tid / 7, px = tid % 7;
    float x1 = boxes[r * 4 + 0] * 40.f, y1 = boxes[r * 4 + 1] * 40.f;
    float x2 = boxes[r * 4 + 2] * 40.f, y2 = boxes[r * 4 + 3] * 40.f;
    float bw = (x2 - x1) * (1.f / 7.f), bh = (y2 - y1) * (1.f / 7.f);
    float X = x1 + (px + 0.5f) * bw, Y = y1 + (py + 0.5f) * bh;
    bool valid = (X > -1.f) && (X < 40.f) && (Y > -1.f) && (Y < 40.f);
    float x = fminf(fmaxf(X, 0.f), 39.f), y = fminf(fmaxf(Y, 0.f), 39.f);
    float x0f = floorf(x), y0f = floorf(y);
    int x0 = (int)x0f, y0 = (int)y0f;
    int x1i = min(x0 + 1, 39), y1i = min(y0 + 1, 39);
    float lx = x - x0f, ly = y - y0f;
    float vm = valid ? 1.f : 0.f;
    sx0[tid] = x0; sy0[tid] = y0; sx1[tid] = x1i; sy1[tid] = y1i;
    sw00[tid] = (1.f - ly) * (1.f - lx) * vm;
    sw01[tid] = (1.f - ly) * lx * vm;
    sw10[tid] = ly * (1.f - lx) * vm;
    sw11[tid] = ly * lx * vm;
  }
  __syncthreads();
  const int c8 = (tid & 31) * 8;  // 8 channels per thread (16B loads)
  const int pq = tid >> 5;        // position phase 0..7
  const ushort* base = imgTb + (size_t)sf * 409600 + c8;
  ushort* outp = A + (size_t)r * 12544 + c8;
  for (int p = pq; p < 49; p += 8) {
    const us8v a = *(const us8v*)(base + (size_t)(sy0[p] * 40 + sx0[p]) * 256);
    const us8v b = *(const us8v*)(base + (size_t)(sy0[p] * 40 + sx1[p]) * 256);
    const us8v c = *(const us8v*)(base + (size_t)(sy1[p] * 40 + sx0[p]) * 256);
    const us8v d = *(const us8v*)(base + (size_t)(sy1[p] * 40 + sx1[p]) * 256);
    float w00 = sw00[p], w01 = sw01[p], w10 = sw10[p], w11 = sw11[p];
    us8v o;
#pragma unroll
    for (int k = 0; k < 8; ++k)
      o[k] = f2bf(bf2f(a[k]) * w00 + bf2f(b[k]) * w01 + bf2f(c[k]) * w10 + bf2f(d[k]) * w11);
    *(us8v*)(outp + (size_t)p * 256) = o;
  }
}

// ------- 4. GEMM1: [4096,12544]x[512,12544]^T bf16, BK=64, split-K=7, bf16 partials ------
// LDS swizzle (BK=64, 8 chunks/row): slot s of row R holds global chunk s ^ (R&7).
__global__ __launch_bounds__(256) void gemm1_kernel(const ushort* __restrict__ A,
                                                    const ushort* __restrict__ B,
                                                    ushort* __restrict__ P) {
  constexpr int K = 12544;
  constexpr int KS = 1792;  // = K/7, 28 iters of 64
  __shared__ __align__(16) ushort sA[128 * 64];  // 16 KB
  __shared__ __align__(16) ushort sB[128 * 64];  // 16 KB
  const int tid = threadIdx.x;
  const int lane = tid & 63, wave = tid >> 6;
  const int wm = wave >> 1, wn = wave & 1;
  const int r16 = lane & 15, quad = lane >> 4;
  const int r0 = blockIdx.x * 128, c0 = blockIdx.y * 128;
  const int kStart = blockIdx.z * KS, kEnd = kStart + KS;
  const ushort* Ab = A + (size_t)r0 * K;
  const ushort* Bb = B + (size_t)c0 * K;
  const int row8 = tid >> 3;                        // 0..31
  const int koff = (((tid & 7) ^ (row8 & 7))) * 8;  // swizzled source chunk offset
  const int sw = r16 & 7;
  f32x4 acc[4][4] = {};
  for (int kk = kStart; kk < kEnd; kk += 64) {
    __syncthreads();
#pragma unroll
    for (int s = 0; s < 4; ++s)
      async16(Ab + (size_t)(s * 32 + row8) * K + kk + koff, (char*)sA + s * 4096 + tid * 16);
#pragma unroll
    for (int s = 0; s < 4; ++s)
      async16(Bb + (size_t)(s * 32 + row8) * K + kk + koff, (char*)sB + s * 4096 + tid * 16);
    __syncthreads();
#pragma unroll
    for (int h = 0; h < 2; ++h) {
      const int slot = ((h * 4 + quad) ^ sw) * 8;
      bf16x8 af[4], bfr[4];
#pragma unroll
      for (int i = 0; i < 4; ++i)
        af[i] = *(const bf16x8*)(sA + (wm * 64 + i * 16 + r16) * 64 + slot);
#pragma unroll
      for (int j = 0; j < 4; ++j)
        bfr[j] = *(const bf16x8*)(sB + (wn * 64 + j * 16 + r16) * 64 + slot);
#pragma unroll
      for (int i = 0; i < 4; ++i)
#pragma unroll
        for (int j = 0; j < 4; ++j)
          acc[i][j] = __builtin_amdgcn_mfma_f32_16x16x32_bf16(af[i], bfr[j], acc[i][j], 0, 0, 0);
    }
  }
  ushort* Pz = P + ((size_t)blockIdx.z * 4096 + r0) * 512 + c0;
#pragma unroll
  for (int i = 0; i < 4; ++i)
#pragma unroll
    for (int j = 0; j < 4; ++j)
#pragma unroll
      for (int g = 0; g < 4; ++g)
        Pz[(size_t)(wm * 64 + i * 16 + quad * 4 + g) * 512 + (wn * 64 + j * 16 + r16)] =
            f2bf(acc[i][j][g]);
}

// ------- 5. combine 7 split-K bf16 partials + b1 + BN1 + ReLU -> h1 bf16 -----------------
__global__ __launch_bounds__(256) void combine_kernel(const ushort* __restrict__ P,
                                                      const float* __restrict__ b1,
                                                      const float* __restrict__ g1,
                                                      const float* __restrict__ bt1,
                                                      const float* __restrict__ m1,
                                                      const float* __restrict__ v1,
                                                      ushort* __restrict__ h1) {
  size_t i = (size_t)blockIdx.x * 256 + threadIdx.x;  // exactly 4096*512
  int col = (int)(i & 511);
  float x = 0.f;
#pragma unroll
  for (int z = 0; z < 7; ++z) x += bf2f(P[i + (size_t)z * 2097152]);
  float s = g1[col] * rsqrtf(v1[col] + BN_EPS);
  float val = fmaxf((x + b1[col] - m1[col]) * s + bt1[col], 0.f);
  h1[i] = f2bf(val);
}

// ------- 6. GEMM2 (64x128 tile, BK=64) + b2 + BN2 + ReLU + group-of-8 max -> out ---------
__global__ __launch_bounds__(256) void gemm2_kernel(const ushort* __restrict__ A,
                                                    const ushort* __restrict__ B,
                                                    const float* __restrict__ b2,
                                                    const float* __restrict__ g2,
                                                    const float* __restrict__ bt2,
                                                    const float* __restrict__ m2,
                                                    const float* __restrict__ v2,
                                                    float* __restrict__ out) {
  constexpr int K = 512;
  __shared__ __align__(16) ushort sA[64 * 64];   // 8 KB
  __shared__ __align__(16) ushort sB[128 * 64];  // 16 KB
  __shared__ ushort st[64 * 128];                // post-activation tile for group-max
  const int tid = threadIdx.x;
  const int lane = tid & 63, wave = tid >> 6;
  const int wm = wave >> 1, wn = wave & 1;  // waves: 2 (rows) x 2 (cols)
  const int r16 = lane & 15, quad = lane >> 4;
  const int r0 = blockIdx.x * 64, c0 = blockIdx.y * 128;
  const ushort* Ab = A + (size_t)r0 * K;
  const ushort* Bb = B + (size_t)c0 * K;
  const int row8 = tid >> 3;
  const int koff = (((tid & 7) ^ (row8 & 7))) * 8;
  const int sw = r16 & 7;
  f32x4 acc[2][4] = {};
  for (int kk = 0; kk < K; kk += 64) {
    __syncthreads();
#pragma unroll
    for (int s = 0; s < 2; ++s)
      async16(Ab + (size_t)(s * 32 + row8) * K + kk + koff, (char*)sA + s * 4096 + tid * 16);
#pragma unroll
    for (int s = 0; s < 4; ++s)
      async16(Bb + (size_t)(s * 32 + row8) * K + kk + koff, (char*)sB + s * 4096 + tid * 16);
    __syncthreads();
#pragma unroll
    for (int h = 0; h < 2; ++h) {
      const int slot = ((h * 4 + quad) ^ sw) * 8;
      bf16x8 af[2], bfr[4];
#pragma unroll
      for (int i = 0; i < 2; ++i)
        af[i] = *(const bf16x8*)(sA + (wm * 32 + i * 16 + r16) * 64 + slot);
#pragma unroll
      for (int j = 0; j < 4; ++j)
        bfr[j] = *(const bf16x8*)(sB + (wn * 64 + j * 16 + r16) * 64 + slot);
#pragma unroll
      for (int i = 0; i < 2; ++i)
#pragma unroll
        for (int j = 0; j < 4; ++j)
          acc[i][j] = __builtin_amdgcn_mfma_f32_16x16x32_bf16(af[i], bfr[j], acc[i][j], 0, 0, 0);
    }
  }
  // epilogue: bias + BN + relu, stage to LDS
  float ss[4], tt[4], bbv[4];
#pragma unroll
  for (int j = 0; j < 4; ++j) {
    int c = c0 + wn * 64 + j * 16 + r16;
    float s = g2[c] * rsqrtf(v2[c] + BN_EPS);
    ss[j] = s; tt[j] = bt2[c] - m2[c] * s; bbv[j] = b2[c];
  }
#pragma unroll
  for (int i = 0; i < 2; ++i)
#pragma unroll
    for (int j = 0; j < 4; ++j)
#pragma unroll
      for (int g = 0; g < 4; ++g) {
        int rr = wm * 32 + i * 16 + quad * 4 + g;
        int cc = wn * 64 + j * 16 + r16;
        float x = (acc[i][j][g] + bbv[j]) * ss[j] + tt[j];
        st[rr * 128 + cc] = f2bf(fmaxf(x, 0.f));
      }
  __syncthreads();
  // 64 rows = 8 complete groups of 8; reduce and store (no atomics)
  for (int e = tid; e < 1024; e += 256) {
    int gg = e >> 7, cc = e & 127;
    float m = 0.f;  // relu output >= 0
#pragma unroll
    for (int k = 0; k < 8; ++k) m = fmaxf(m, bf2f(st[(gg * 8 + k) * 128 + cc]));
    out[(size_t)(r0 / 8 + gg) * 512 + c0 + cc] = m;
  }
}

extern "C" void kernel_launch(void* const* d_in, const int* in_sizes, int n_in,
                              void* d_out, int out_size, void* d_ws, size_t ws_size,
                              hipStream_t stream) {
  (void)in_sizes; (void)n_in; (void)out_size; (void)ws_size;
  const float* images = (const float*)d_in[0];
  const int* kf      = (const int*)d_in[1];
  const float* boxes = (const float*)d_in[2];
  const float* w1    = (const float*)d_in[3];
  const float* b1    = (const float*)d_in[4];
  const float* g1    = (const float*)d_in[5];
  const float* bt1   = (const float*)d_in[6];
  const float* m1    = (const float*)d_in[7];
  const float* v1    = (const float*)d_in[8];
  const float* w2    = (const float*)d_in[9];
  const float* b2    = (const float*)d_in[10];
  const float* g2    = (const float*)d_in[11];
  const float* bt2   = (const float*)d_in[12];
  const float* m2    = (const float*)d_in[13];
  const float* v2    = (const float*)d_in[14];
  float* out = (float*)d_out;

  char* ws = (char*)d_ws;
  // layout (bytes):  [ws_size >= 221 MB proven in round 1]
  //   A     @ 0          : 4096*12544*2 = 102,760,448
  //   w1b   @ 102,760,448: 512*12544*2  =  12,845,056
  //   w2b   @ 115,605,504: 512*512*2    =     524,288
  //   imgTb @ 116,129,792: 64*1600*256*2 = 52,428,800 -> ends 168,558,592 (dead after roi)
  //   P     @ 116,129,792: 7*4096*512*2 = 29,360,128  (aliases imgTb head; written post-roi)
  //   h1    @ 149,684,224: 4096*512*2   =  4,194,304  (aliases imgTb mid; written post-roi)
  //   perm  @ 168,558,592: 4096*4       =      16,384 (AFTER imgTb end — R8 bug: perm was
  //                                                    inside imgTb, clobbered by transpose)
  ushort* Abuf  = (ushort*)(ws + 0);
  ushort* w1b   = (ushort*)(ws + 102760448);
  ushort* w2b   = (ushort*)(ws + 115605504);
  ushort* imgTb = (ushort*)(ws + 116129792);
  ushort* P     = (ushort*)(ws + 116129792);
  ushort* h1    = (ushort*)(ws + 149684224);
  int*    perm  = (int*)(ws + 168558592);

  hipLaunchKernelGGL(sort_kernel, dim3(1), dim3(256), 0, stream, kf, perm);
  hipLaunchKernelGGL(transpose_kernel, dim3(64, 25), dim3(256), 0, stream, images, imgTb);
  hipLaunchKernelGGL(wconvert_kernel, dim3(1536), dim3(256), 0, stream, w1, w1b, w2, w2b);
  hipLaunchKernelGGL(roi_kernel, dim3(4096), dim3(256), 0, stream, imgTb, kf, boxes, perm, Abuf);
  hipLaunchKernelGGL(gemm1_kernel, dim3(32, 4, 7), dim3(256), 0, stream, Abuf, w1b, P);
  hipLaunchKernelGGL(combine_kernel, dim3(8192), dim3(256), 0, stream, P, b1, g1, bt1, m1, v1, h1);
  hipLaunchKernelGGL(gemm2_kernel, dim3(64, 4), dim3(256), 0, stream, h1, w2b, b2, g2, bt2, m2, v2, out);
}

// Round 10
// 304.029 us; speedup vs baseline: 1.1702x; 1.1111x over previous
//
#include <hip/hip_runtime.h>

// NodeEncoder: RoIAlign -> FC1(12544->512)+BN+ReLU -> FC2(512->512)+BN+ReLU -> max over K=8
// F=64 C=256 H=W=40, N=512 K=8 (R=4096), ROI=7, HID=D=512
// NOTE: harness re-poisons 400MiB d_ws (~61us fill) + restores inputs (~45us) inside the
// timed region -> ~106us fixed overhead. Kernel budget is what we optimize.

typedef __bf16 bf16x8 __attribute__((ext_vector_type(8)));
typedef float f32x4 __attribute__((ext_vector_type(4)));
typedef ushort us8v __attribute__((ext_vector_type(8)));

#define BN_EPS 1e-3f

__device__ __forceinline__ ushort f2bf(float f) {
  union { float f; unsigned u; } v; v.f = f;
  unsigned r = (v.u + 0x7FFFu + ((v.u >> 16) & 1u)) >> 16;
  return (ushort)r;
}
__device__ __forceinline__ float bf2f(ushort b) {
  union { unsigned u; float f; } v; v.u = ((unsigned)b) << 16;
  return v.f;
}
__device__ __forceinline__ void async16(const void* g, void* l) {
  __builtin_amdgcn_global_load_lds((const __attribute__((address_space(1))) void*)g,
                                   (__attribute__((address_space(3))) void*)l, 16, 0, 0);
}

// ------- 1. prep: transpose (blocks 0..1599) | w1 conv (1600..2111) | w2 conv (2112..3135)
//            | RoI frame-sort (3136). Independent jobs merged to cut launch/drain gaps.
__global__ __launch_bounds__(256) void prep_kernel(const float* __restrict__ img,
                                                   ushort* __restrict__ imgTb,
                                                   const float* __restrict__ w1,
                                                   ushort* __restrict__ w1b,
                                                   const float* __restrict__ w2,
                                                   ushort* __restrict__ w2b,
                                                   const int* __restrict__ kf,
                                                   int* __restrict__ perm) {
  __shared__ char smem[50384];  // union: transpose 33,280 B | w1 tile 50,372 B | sort 512 B
  const int b = blockIdx.x;
  const int tid = threadIdx.x;
  if (b < 1600) {
    // images [64,256,40,40] f32 -> imgTb [64,40,40,256] bf16; 256ch x 64px tile
    ushort* lds = (ushort*)smem;  // [pixel][channel], pitch 260
    const int f = b / 25, p0 = (b % 25) * 64;
    const float* src = img + (size_t)f * 409600 + p0;
#pragma unroll
    for (int m = 0; m < 4; ++m) {
      int g = m * 256 + tid;
      int cg = g >> 4;   // channel group (4 ch)
      int pg = g & 15;   // pixel group (4 px)
      float4 v[4];
#pragma unroll
      for (int j = 0; j < 4; ++j)
        v[j] = *(const float4*)(src + (size_t)(cg * 4 + j) * 1600 + pg * 4);
#pragma unroll
      for (int i = 0; i < 4; ++i) {
        ushort4 o;
        o.x = f2bf((&v[0].x)[i]);
        o.y = f2bf((&v[1].x)[i]);
        o.z = f2bf((&v[2].x)[i]);
        o.w = f2bf((&v[3].x)[i]);
        *(ushort4*)(&lds[(pg * 4 + i) * 260 + cg * 4]) = o;
      }
    }
    __syncthreads();
    ushort* dst = imgTb + ((size_t)f * 1600 + p0) * 256;
#pragma unroll
    for (int q = 0; q < 8; ++q) {
      int p = q * 8 + (tid >> 5);
      int cg8 = tid & 31;
      ushort4 a = *(const ushort4*)(&lds[p * 260 + cg8 * 8]);
      ushort4 c = *(const ushort4*)(&lds[p * 260 + cg8 * 8 + 4]);
      us8v o;
      o[0] = a.x; o[1] = a.y; o[2] = a.z; o[3] = a.w;
      o[4] = c.x; o[5] = c.y; o[6] = c.z; o[7] = c.w;
      *(us8v*)(dst + (size_t)p * 256 + cg8 * 8) = o;
    }
  } else if (b < 2112) {
    // w1 [512][256][49] f32 -> w1b [512][49*256] bf16 (k = p*256+c)
    float* t = (float*)smem;  // [p][c], pitch 257
    const int o = b - 1600;
    const float* src = w1 + (size_t)o * 12544;
    for (int j = tid; j < 12544; j += 256) {
      int c = j / 49, p = j - c * 49;
      t[p * 257 + c] = src[j];
    }
    __syncthreads();
    ushort* dst = w1b + (size_t)o * 12544;
    for (int k = tid; k < 12544; k += 256) {
      int p = k >> 8, c = k & 255;
      dst[k] = f2bf(t[p * 257 + c]);
    }
  } else if (b < 3136) {
    size_t i = (size_t)(b - 2112) * 256 + tid;  // exactly 512*512
    w2b[i] = f2bf(w2[i]);
  } else {
    // counting sort of RoIs by frame -> perm[4096]
    int* cnt = (int*)smem;
    int* base = cnt + 64;
    if (tid < 64) cnt[tid] = 0;
    __syncthreads();
    for (int r = tid; r < 4096; r += 256) atomicAdd(&cnt[kf[r]], 1);
    __syncthreads();
    if (tid == 0) {
      int acc = 0;
      for (int f = 0; f < 64; ++f) { base[f] = acc; acc += cnt[f]; }
    }
    __syncthreads();
    for (int r = tid; r < 4096; r += 256) {
      int p = atomicAdd(&base[kf[r]], 1);
      perm[p] = r;
    }
  }
}

// ------- 2. RoIAlign (bf16 image) -> A [4096][12544] bf16, k = (py*7+px)*256 + c ---------
// XCD-locality: perm is frame-sorted; blocks with same (blockIdx&7) share an XCD and walk
// ~8 consecutive frames -> gathers stay in that XCD's 4MB L2. [R9: -16us validated]
__global__ __launch_bounds__(256) void roi_kernel(const ushort* __restrict__ imgTb,
                                                  const int* __restrict__ kf,
                                                  const float* __restrict__ boxes,
                                                  const int* __restrict__ perm,
                                                  ushort* __restrict__ A) {
  __shared__ int sy0[49], sx0[49], sy1[49], sx1[49];
  __shared__ float sw00[49], sw01[49], sw10[49], sw11[49];
  __shared__ int sf, sr;
  const int tid = threadIdx.x;
  if (tid == 0) {
    int r = perm[((blockIdx.x & 7) << 9) | (blockIdx.x >> 3)];
    sr = r;
    sf = kf[r];
  }
  __syncthreads();
  const int r = sr;
  if (tid < 49) {
    int py = tid / 7, px = tid % 7;
    float x1 = boxes[r * 4 + 0] * 40.f, y1 = boxes[r * 4 + 1] * 40.f;
    float x2 = boxes[r * 4 + 2] * 40.f, y2 = boxes[r * 4 + 3] * 40.f;
    float bw = (x2 - x1) * (1.f / 7.f), bh = (y2 - y1) * (1.f / 7.f);
    float X = x1 + (px + 0.5f) * bw, Y = y1 + (py + 0.5f) * bh;
    bool valid = (X > -1.f) && (X < 40.f) && (Y > -1.f) && (Y < 40.f);
    float x = fminf(fmaxf(X, 0.f), 39.f), y = fminf(fmaxf(Y, 0.f), 39.f);
    float x0f = floorf(x), y0f = floorf(y);
    int x0 = (int)x0f, y0 = (int)y0f;
    int x1i = min(x0 + 1, 39), y1i = min(y0 + 1, 39);
    float lx = x - x0f, ly = y - y0f;
    float vm = valid ? 1.f : 0.f;
    sx0[tid] = x0; sy0[tid] = y0; sx1[tid] = x1i; sy1[tid] = y1i;
    sw00[tid] = (1.f - ly) * (1.f - lx) * vm;
    sw01[tid] = (1.f - ly) * lx * vm;
    sw10[tid] = ly * (1.f - lx) * vm;
    sw11[tid] = ly * lx * vm;
  }
  __syncthreads();
  const int c8 = (tid & 31) * 8;
  const int pq = tid >> 5;
  const ushort* base = imgTb + (size_t)sf * 409600 + c8;
  ushort* outp = A + (size_t)r * 12544 + c8;
  for (int p = pq; p < 49; p += 8) {
    const us8v a = *(const us8v*)(base + (size_t)(sy0[p] * 40 + sx0[p]) * 256);
    const us8v b = *(const us8v*)(base + (size_t)(sy0[p] * 40 + sx1[p]) * 256);
    const us8v c = *(const us8v*)(base + (size_t)(sy1[p] * 40 + sx0[p]) * 256);
    const us8v d = *(const us8v*)(base + (size_t)(sy1[p] * 40 + sx1[p]) * 256);
    float w00 = sw00[p], w01 = sw01[p], w10 = sw10[p], w11 = sw11[p];
    us8v o;
#pragma unroll
    for (int k = 0; k < 8; ++k)
      o[k] = f2bf(bf2f(a[k]) * w00 + bf2f(b[k]) * w01 + bf2f(c[k]) * w10 + bf2f(d[k]) * w11);
    *(us8v*)(outp + (size_t)p * 256) = o;
  }
}

// ------- 3. GEMM1: [4096,12544]x[512,12544]^T bf16, BK=64, split-K=7, bf16 partials ------
// __launch_bounds__(256,4): force <=128 unified regs/wave (64 acc AGPR + <=64 VGPR) so
// 4 blocks/CU fit (was 3 at 140 regs) -> more cross-block overlap of the barrier drain.
// LDS swizzle (BK=64, 8 chunks/row): slot s of row R holds global chunk s ^ (R&7).
__global__ __launch_bounds__(256, 4) void gemm1_kernel(const ushort* __restrict__ A,
                                                       const ushort* __restrict__ B,
                                                       ushort* __restrict__ P) {
  constexpr int K = 12544;
  constexpr int KS = 1792;  // = K/7, 28 iters of 64
  __shared__ __align__(16) ushort sA[128 * 64];  // 16 KB
  __shared__ __align__(16) ushort sB[128 * 64];  // 16 KB
  const int tid = threadIdx.x;
  const int lane = tid & 63, wave = tid >> 6;
  const int wm = wave >> 1, wn = wave & 1;
  const int r16 = lane & 15, quad = lane >> 4;
  const int r0 = blockIdx.x * 128, c0 = blockIdx.y * 128;
  const int kStart = blockIdx.z * KS, kEnd = kStart + KS;
  const ushort* Ab = A + (size_t)r0 * K;
  const ushort* Bb = B + (size_t)c0 * K;
  const int row8 = tid >> 3;                        // 0..31
  const int koff = (((tid & 7) ^ (row8 & 7))) * 8;  // swizzled source chunk offset
  const int sw = r16 & 7;
  f32x4 acc[4][4] = {};
  for (int kk = kStart; kk < kEnd; kk += 64) {
    __syncthreads();
#pragma unroll
    for (int s = 0; s < 4; ++s)
      async16(Ab + (size_t)(s * 32 + row8) * K + kk + koff, (char*)sA + s * 4096 + tid * 16);
#pragma unroll
    for (int s = 0; s < 4; ++s)
      async16(Bb + (size_t)(s * 32 + row8) * K + kk + koff, (char*)sB + s * 4096 + tid * 16);
    __syncthreads();
#pragma unroll
    for (int h = 0; h < 2; ++h) {
      const int slot = ((h * 4 + quad) ^ sw) * 8;
      bf16x8 af[4], bfr[4];
#pragma unroll
      for (int i = 0; i < 4; ++i)
        af[i] = *(const bf16x8*)(sA + (wm * 64 + i * 16 + r16) * 64 + slot);
#pragma unroll
      for (int j = 0; j < 4; ++j)
        bfr[j] = *(const bf16x8*)(sB + (wn * 64 + j * 16 + r16) * 64 + slot);
#pragma unroll
      for (int i = 0; i < 4; ++i)
#pragma unroll
        for (int j = 0; j < 4; ++j)
          acc[i][j] = __builtin_amdgcn_mfma_f32_16x16x32_bf16(af[i], bfr[j], acc[i][j], 0, 0, 0);
    }
  }
  ushort* Pz = P + ((size_t)blockIdx.z * 4096 + r0) * 512 + c0;
#pragma unroll
  for (int i = 0; i < 4; ++i)
#pragma unroll
    for (int j = 0; j < 4; ++j)
#pragma unroll
      for (int g = 0; g < 4; ++g)
        Pz[(size_t)(wm * 64 + i * 16 + quad * 4 + g) * 512 + (wn * 64 + j * 16 + r16)] =
            f2bf(acc[i][j][g]);
}

// ------- 4. combine 7 split-K bf16 partials + b1 + BN1 + ReLU -> h1 bf16 -----------------
__global__ __launch_bounds__(256) void combine_kernel(const ushort* __restrict__ P,
                                                      const float* __restrict__ b1,
                                                      const float* __restrict__ g1,
                                                      const float* __restrict__ bt1,
                                                      const float* __restrict__ m1,
                                                      const float* __restrict__ v1,
                                                      ushort* __restrict__ h1) {
  size_t i = (size_t)blockIdx.x * 256 + threadIdx.x;  // exactly 4096*512
  int col = (int)(i & 511);
  float x = 0.f;
#pragma unroll
  for (int z = 0; z < 7; ++z) x += bf2f(P[i + (size_t)z * 2097152]);
  float s = g1[col] * rsqrtf(v1[col] + BN_EPS);
  float val = fmaxf((x + b1[col] - m1[col]) * s + bt1[col], 0.f);
  h1[i] = f2bf(val);
}

// ------- 5. GEMM2 (64x128 tile, BK=64) + b2 + BN2 + ReLU + group-of-8 max -> out ---------
__global__ __launch_bounds__(256) void gemm2_kernel(const ushort* __restrict__ A,
                                                    const ushort* __restrict__ B,
                                                    const float* __restrict__ b2,
                                                    const float* __restrict__ g2,
                                                    const float* __restrict__ bt2,
                                                    const float* __restrict__ m2,
                                                    const float* __restrict__ v2,
                                                    float* __restrict__ out) {
  constexpr int K = 512;
  __shared__ __align__(16) ushort sA[64 * 64];   // 8 KB
  __shared__ __align__(16) ushort sB[128 * 64];  // 16 KB
  __shared__ ushort st[64 * 128];                // post-activation tile for group-max
  const int tid = threadIdx.x;
  const int lane = tid & 63, wave = tid >> 6;
  const int wm = wave >> 1, wn = wave & 1;
  const int r16 = lane & 15, quad = lane >> 4;
  const int r0 = blockIdx.x * 64, c0 = blockIdx.y * 128;
  const ushort* Ab = A + (size_t)r0 * K;
  const ushort* Bb = B + (size_t)c0 * K;
  const int row8 = tid >> 3;
  const int koff = (((tid & 7) ^ (row8 & 7))) * 8;
  const int sw = r16 & 7;
  f32x4 acc[2][4] = {};
  for (int kk = 0; kk < K; kk += 64) {
    __syncthreads();
#pragma unroll
    for (int s = 0; s < 2; ++s)
      async16(Ab + (size_t)(s * 32 + row8) * K + kk + koff, (char*)sA + s * 4096 + tid * 16);
#pragma unroll
    for (int s = 0; s < 4; ++s)
      async16(Bb + (size_t)(s * 32 + row8) * K + kk + koff, (char*)sB + s * 4096 + tid * 16);
    __syncthreads();
#pragma unroll
    for (int h = 0; h < 2; ++h) {
      const int slot = ((h * 4 + quad) ^ sw) * 8;
      bf16x8 af[2], bfr[4];
#pragma unroll
      for (int i = 0; i < 2; ++i)
        af[i] = *(const bf16x8*)(sA + (wm * 32 + i * 16 + r16) * 64 + slot);
#pragma unroll
      for (int j = 0; j < 4; ++j)
        bfr[j] = *(const bf16x8*)(sB + (wn * 64 + j * 16 + r16) * 64 + slot);
#pragma unroll
      for (int i = 0; i < 2; ++i)
#pragma unroll
        for (int j = 0; j < 4; ++j)
          acc[i][j] = __builtin_amdgcn_mfma_f32_16x16x32_bf16(af[i], bfr[j], acc[i][j], 0, 0, 0);
    }
  }
  float ss[4], tt[4], bbv[4];
#pragma unroll
  for (int j = 0; j < 4; ++j) {
    int c = c0 + wn * 64 + j * 16 + r16;
    float s = g2[c] * rsqrtf(v2[c] + BN_EPS);
    ss[j] = s; tt[j] = bt2[c] - m2[c] * s; bbv[j] = b2[c];
  }
#pragma unroll
  for (int i = 0; i < 2; ++i)
#pragma unroll
    for (int j = 0; j < 4; ++j)
#pragma unroll
      for (int g = 0; g < 4; ++g) {
        int rr = wm * 32 + i * 16 + quad * 4 + g;
        int cc = wn * 64 + j * 16 + r16;
        float x = (acc[i][j][g] + bbv[j]) * ss[j] + tt[j];
        st[rr * 128 + cc] = f2bf(fmaxf(x, 0.f));
      }
  __syncthreads();
  for (int e = tid; e < 1024; e += 256) {
    int gg = e >> 7, cc = e & 127;
    float m = 0.f;  // relu output >= 0
#pragma unroll
    for (int k = 0; k < 8; ++k) m = fmaxf(m, bf2f(st[(gg * 8 + k) * 128 + cc]));
    out[(size_t)(r0 / 8 + gg) * 512 + c0 + cc] = m;
  }
}

extern "C" void kernel_launch(void* const* d_in, const int* in_sizes, int n_in,
                              void* d_out, int out_size, void* d_ws, size_t ws_size,
                              hipStream_t stream) {
  (void)in_sizes; (void)n_in; (void)out_size; (void)ws_size;
  const float* images = (const float*)d_in[0];
  const int* kf      = (const int*)d_in[1];
  const float* boxes = (const float*)d_in[2];
  const float* w1    = (const float*)d_in[3];
  const float* b1    = (const float*)d_in[4];
  const float* g1    = (const float*)d_in[5];
  const float* bt1   = (const float*)d_in[6];
  const float* m1    = (const float*)d_in[7];
  const float* v1    = (const float*)d_in[8];
  const float* w2    = (const float*)d_in[9];
  const float* b2    = (const float*)d_in[10];
  const float* g2    = (const float*)d_in[11];
  const float* bt2   = (const float*)d_in[12];
  const float* m2    = (const float*)d_in[13];
  const float* v2    = (const float*)d_in[14];
  float* out = (float*)d_out;

  char* ws = (char*)d_ws;
  // layout (bytes):  [ws_size >= 221 MB proven in round 1]
  //   A     @ 0          : 4096*12544*2 = 102,760,448
  //   w1b   @ 102,760,448: 512*12544*2  =  12,845,056
  //   w2b   @ 115,605,504: 512*512*2    =     524,288
  //   imgTb @ 116,129,792: 64*1600*256*2 = 52,428,800 -> ends 168,558,592 (dead after roi)
  //   P     @ 116,129,792: 7*4096*512*2 = 29,360,128  (aliases imgTb head; written post-roi)
  //   h1    @ 149,684,224: 4096*512*2   =  4,194,304  (aliases imgTb mid; written post-roi)
  //   perm  @ 168,558,592: 4096*4       =      16,384 (strictly after imgTb end!)
  ushort* Abuf  = (ushort*)(ws + 0);
  ushort* w1b   = (ushort*)(ws + 102760448);
  ushort* w2b   = (ushort*)(ws + 115605504);
  ushort* imgTb = (ushort*)(ws + 116129792);
  ushort* P     = (ushort*)(ws + 116129792);
  ushort* h1    = (ushort*)(ws + 149684224);
  int*    perm  = (int*)(ws + 168558592);

  hipLaunchKernelGGL(prep_kernel, dim3(3137), dim3(256), 0, stream,
                     images, imgTb, w1, w1b, w2, w2b, kf, perm);
  hipLaunchKernelGGL(roi_kernel, dim3(4096), dim3(256), 0, stream, imgTb, kf, boxes, perm, Abuf);
  hipLaunchKernelGGL(gemm1_kernel, dim3(32, 4, 7), dim3(256), 0, stream, Abuf, w1b, P);
  hipLaunchKernelGGL(combine_kernel, dim3(8192), dim3(256), 0, stream, P, b1, g1, bt1, m1, v1, h1);
  hipLaunchKernelGGL(gemm2_kernel, dim3(64, 4), dim3(256), 0, stream, h1, w2b, b2, g2, bt2, m2, v2, out);
}